// Round 4
// baseline (308.903 us; speedup 1.0000x reference)
//
#include <hip/hip_runtime.h>
#include <hip/hip_bf16.h>

#define N_ROWS 20000
#define KNN 32
#define DIN 128
#define DOUT 128

// ---- kernel 0: pack transposed/fused weight layout ----
// WTp float layout: [d4][j][i] where d = d4*4+i, j in [0,256)
//   j <  128 : channel j of XA, weight wh[j][d]        (multiplies messages)
//   j >= 128 : channel j-128 of XB, weight wh[j-128][128+d] (multiplies self)
__global__ __launch_bounds__(256) void pack_wt(const float* __restrict__ wh,
                                               float* __restrict__ WTp) {
    int tid = blockIdx.x * 256 + threadIdx.x;  // 0..32767
    int i  = tid & 3;
    int j  = (tid >> 2) & 255;
    int d4 = tid >> 10;
    int d  = d4 * 4 + i;
    float v = (j < 128) ? wh[j * 256 + d] : wh[(j - 128) * 256 + 128 + d];
    WTp[tid] = v;
}

// ---- kernel 1: XA[n][o] = x[n]·wh[o,:128] ; XB'[n][o] = x[n]·wh[o,128:] + bh[o]
// block = 256 threads, tile = 64 rows x 256 channels.
// thread (tx = t&63, ty = t>>6): rows ty*16..ty*16+15, channels {tx, tx+64, tx+128, tx+192}
__global__ __launch_bounds__(256) void gemm_xaxb(const float* __restrict__ x,
                                                 const float* __restrict__ WTp,
                                                 const float* __restrict__ bh,
                                                 float* __restrict__ XA,
                                                 float* __restrict__ XBp) {
    __shared__ float xs[64][128];   // 32 KB
    const int t = threadIdx.x;
    const int row0 = blockIdx.x * 64;

    // stage x tile (coalesced float4)
    #pragma unroll
    for (int i = 0; i < 8; ++i) {
        int idx = t + i * 256;          // float4 slot in [0,2048)
        int r = idx >> 5, c4 = idx & 31;
        int gr = row0 + r; if (gr > N_ROWS - 1) gr = N_ROWS - 1;
        float4 v = ((const float4*)(x + (size_t)gr * DIN))[c4];
        ((float4*)xs[r])[c4] = v;
    }
    __syncthreads();

    const int tx = t & 63;
    const int ty = t >> 6;
    const int r0 = ty * 16;
    float acc[16][4];
    #pragma unroll
    for (int r = 0; r < 16; ++r)
        #pragma unroll
        for (int c = 0; c < 4; ++c) acc[r][c] = 0.f;

    const float4* W4 = (const float4*)WTp;
    for (int d4 = 0; d4 < 32; ++d4) {
        float4 w0 = W4[d4 * 256 + tx];         // channel tx       (XA)
        float4 w1 = W4[d4 * 256 + 64 + tx];    // channel tx+64    (XA)
        float4 w2 = W4[d4 * 256 + 128 + tx];   // channel tx       (XB)
        float4 w3 = W4[d4 * 256 + 192 + tx];   // channel tx+64    (XB)
        #pragma unroll
        for (int r = 0; r < 16; ++r) {
            float4 xv = ((const float4*)xs[r0 + r])[d4];  // wave-uniform broadcast
            acc[r][0] += xv.x * w0.x + xv.y * w0.y + xv.z * w0.z + xv.w * w0.w;
            acc[r][1] += xv.x * w1.x + xv.y * w1.y + xv.z * w1.z + xv.w * w1.w;
            acc[r][2] += xv.x * w2.x + xv.y * w2.y + xv.z * w2.z + xv.w * w2.w;
            acc[r][3] += xv.x * w3.x + xv.y * w3.y + xv.z * w3.z + xv.w * w3.w;
        }
    }

    float bh0 = bh[tx], bh1 = bh[64 + tx];
    #pragma unroll
    for (int r = 0; r < 16; ++r) {
        int gr = row0 + r0 + r;
        if (gr < N_ROWS) {
            XA [(size_t)gr * DOUT + tx]       = acc[r][0];
            XA [(size_t)gr * DOUT + 64 + tx]  = acc[r][1];
            XBp[(size_t)gr * DOUT + tx]       = acc[r][2] + bh0;
            XBp[(size_t)gr * DOUT + 64 + tx]  = acc[r][3] + bh1;
        }
    }
}

// ---- kernel 2: fused distance-MLP + gather + relu + position dot + structure mean
// one block per n, 128 threads = output channel o
__global__ __launch_bounds__(128) void fused_main(const float* __restrict__ dists,
                                                  const int*  __restrict__ argm,
                                                  const float* __restrict__ w1d,
                                                  const float* __restrict__ b1d,
                                                  const float* __restrict__ w2d,
                                                  const float* __restrict__ b2d,
                                                  const float* __restrict__ wp,
                                                  const float* __restrict__ bp,
                                                  const float* __restrict__ XA,
                                                  const float* __restrict__ XBp,
                                                  float* __restrict__ out_pos,
                                                  float* __restrict__ out_struct) {
    const int n = blockIdx.x;
    const int t = threadIdx.x;   // 0..127
    __shared__ float d_lds[KNN];
    __shared__ int   idx_lds[KNN];
    __shared__ float pos_part[2][KNN];

    // distance MLP: d(n,k) = sum_o relu(s*w1d[o]+b1d[o])*w2d[o] + b2d
    // 4 lanes per k, each handles 32 o's
    {
        int k = t >> 2, sub = t & 3;
        float s = dists[(size_t)n * KNN + k];
        float a = 0.f;
        int ob = sub * 32;
        #pragma unroll
        for (int o4 = 0; o4 < 8; ++o4) {
            float4 w1 = ((const float4*)(w1d + ob))[o4];
            float4 b1 = ((const float4*)(b1d + ob))[o4];
            float4 w2 = ((const float4*)(w2d + ob))[o4];
            a += fmaxf(fmaf(s, w1.x, b1.x), 0.f) * w2.x;
            a += fmaxf(fmaf(s, w1.y, b1.y), 0.f) * w2.y;
            a += fmaxf(fmaf(s, w1.z, b1.z), 0.f) * w2.z;
            a += fmaxf(fmaf(s, w1.w, b1.w), 0.f) * w2.w;
        }
        a += __shfl_xor(a, 1);
        a += __shfl_xor(a, 2);
        if (sub == 0) d_lds[k] = a + b2d[0];
        if (t < KNN) idx_lds[t] = argm[(size_t)n * KNN + t];
    }

    float base = XBp[(size_t)n * DOUT + t];   // XB + bh, per-channel
    float wpv  = wp[t];
    __syncthreads();

    const int lane = t & 63;
    const int w    = t >> 6;
    float sacc = 0.f;

    #pragma unroll 4
    for (int kk = 0; kk < KNN; ++kk) {
        float dk = d_lds[kk];
        int   m  = idx_lds[kk];
        float xa = XA[(size_t)m * DOUT + t];       // gathered row, coalesced
        float h  = fmaxf(fmaf(dk, xa, base), 0.f);
        sacc += h;
        float pv = h * wpv;
        pv += __shfl_xor(pv, 1);
        pv += __shfl_xor(pv, 2);
        pv += __shfl_xor(pv, 4);
        pv += __shfl_xor(pv, 8);
        pv += __shfl_xor(pv, 16);
        pv += __shfl_xor(pv, 32);
        if (lane == 0) pos_part[w][kk] = pv;
    }
    __syncthreads();

    if (t < KNN)
        out_pos[(size_t)n * KNN + t] = pos_part[0][t] + pos_part[1][t] + bp[0];
    out_struct[(size_t)n * DOUT + t] = sacc * (1.f / KNN);
}

extern "C" void kernel_launch(void* const* d_in, const int* in_sizes, int n_in,
                              void* d_out, int out_size, void* d_ws, size_t ws_size,
                              hipStream_t stream) {
    const float* data_x = (const float*)d_in[0];
    const float* dists  = (const float*)d_in[1];
    const int*   argm   = (const int*)d_in[2];
    const float* w1d    = (const float*)d_in[3];
    const float* b1d    = (const float*)d_in[4];
    const float* w2d    = (const float*)d_in[5];
    const float* b2d    = (const float*)d_in[6];
    const float* wh     = (const float*)d_in[7];
    const float* bh     = (const float*)d_in[8];
    const float* wp     = (const float*)d_in[9];
    const float* bp     = (const float*)d_in[10];

    float* out_pos    = (float*)d_out;                       // [N,K]
    float* out_struct = out_pos + (size_t)N_ROWS * KNN;      // [N,DOUT]

    float* XA  = (float*)d_ws;                               // [N,128]
    float* XBp = XA  + (size_t)N_ROWS * DOUT;                // [N,128]
    float* WTp = XBp + (size_t)N_ROWS * DOUT;                // 32768 floats

    pack_wt<<<128, 256, 0, stream>>>(wh, WTp);
    gemm_xaxb<<<(N_ROWS + 63) / 64, 256, 0, stream>>>(data_x, WTp, bh, XA, XBp);
    fused_main<<<N_ROWS, 128, 0, stream>>>(dists, argm, w1d, b1d, w2d, b2d,
                                           wp, bp, XA, XBp, out_pos, out_struct);
}

// Round 7
// 230.810 us; speedup vs baseline: 1.3383x; 1.3383x over previous
//
#include <hip/hip_runtime.h>
#include <hip/hip_bf16.h>

#define N_ROWS 20000
#define KNN 32
#define DIN 128
#define DOUT 128

// ---- kernel 0: pack transposed/fused weight layout ----
// WTp float layout: [d4][j][i] where d = d4*4+i, j in [0,256)
//   j <  128 : channel j of XA (wh[j][d]) ; j >= 128 : channel j-128 of XB (wh[j-128][128+d])
__global__ __launch_bounds__(256) void pack_wt(const float* __restrict__ wh,
                                               float* __restrict__ WTp) {
    int tid = blockIdx.x * 256 + threadIdx.x;  // 0..32767
    int i  = tid & 3;
    int j  = (tid >> 2) & 255;
    int d4 = tid >> 10;
    int d  = d4 * 4 + i;
    float v = (j < 128) ? wh[j * 256 + d] : wh[(j - 128) * 256 + 128 + d];
    WTp[tid] = v;
}

// ---- kernel 1: XA16[n][o] = bf16(x[n]·wh[o,:128]) ; XBp[n][o] = x[n]·wh[o,128:] + bh[o]
// 32-row tiles (625 blocks), 256 threads: tx = t&63 (channel), ty = t>>6, 8 rows/thread
__global__ __launch_bounds__(256) void gemm_xaxb(const float* __restrict__ x,
                                                 const float* __restrict__ WTp,
                                                 const float* __restrict__ bh,
                                                 __hip_bfloat16* __restrict__ XA16,
                                                 float* __restrict__ XBp) {
    __shared__ float xs[32][128];   // 16 KB
    const int t = threadIdx.x;
    const int row0 = blockIdx.x * 32;   // 625*32 == 20000 exactly, no bounds needed

    #pragma unroll
    for (int i = 0; i < 4; ++i) {
        int idx = t + i * 256;          // float4 slot in [0,1024)
        int r = idx >> 5, c4 = idx & 31;
        ((float4*)xs[r])[c4] = ((const float4*)(x + (size_t)(row0 + r) * DIN))[c4];
    }
    __syncthreads();

    const int tx = t & 63;
    const int ty = t >> 6;
    const int r0 = ty * 8;
    float acc[8][4];
    #pragma unroll
    for (int r = 0; r < 8; ++r)
        #pragma unroll
        for (int c = 0; c < 4; ++c) acc[r][c] = 0.f;

    const float4* W4 = (const float4*)WTp;
    for (int d4 = 0; d4 < 32; ++d4) {
        float4 w0 = W4[d4 * 256 + tx];         // XA, channel tx
        float4 w1 = W4[d4 * 256 + 64 + tx];    // XA, channel tx+64
        float4 w2 = W4[d4 * 256 + 128 + tx];   // XB, channel tx
        float4 w3 = W4[d4 * 256 + 192 + tx];   // XB, channel tx+64
        #pragma unroll
        for (int r = 0; r < 8; ++r) {
            float4 xv = ((const float4*)xs[r0 + r])[d4];  // wave-uniform broadcast
            acc[r][0] += xv.x * w0.x + xv.y * w0.y + xv.z * w0.z + xv.w * w0.w;
            acc[r][1] += xv.x * w1.x + xv.y * w1.y + xv.z * w1.z + xv.w * w1.w;
            acc[r][2] += xv.x * w2.x + xv.y * w2.y + xv.z * w2.z + xv.w * w2.w;
            acc[r][3] += xv.x * w3.x + xv.y * w3.y + xv.z * w3.z + xv.w * w3.w;
        }
    }

    float bh0 = bh[tx], bh1 = bh[64 + tx];
    #pragma unroll
    for (int r = 0; r < 8; ++r) {
        size_t gr = row0 + r0 + r;
        XA16[gr * DOUT + tx]       = __float2bfloat16(acc[r][0]);
        XA16[gr * DOUT + 64 + tx]  = __float2bfloat16(acc[r][1]);
        XBp [gr * DOUT + tx]       = acc[r][2] + bh0;
        XBp [gr * DOUT + 64 + tx]  = acc[r][3] + bh1;
    }
}

// ---- kernel 2: fused distance-MLP + bf16 gather + relu + pos/structure reductions
// one block per n, 128 threads = output channel o. No per-iteration shfl chain:
// pos contributions go to LDS (pad 129 -> conflict-free), reduced once at the end.
__global__ __launch_bounds__(128) void fused_main(const float* __restrict__ dists,
                                                  const int*  __restrict__ argm,
                                                  const float* __restrict__ w1d,
                                                  const float* __restrict__ b1d,
                                                  const float* __restrict__ w2d,
                                                  const float* __restrict__ b2d,
                                                  const float* __restrict__ wp,
                                                  const float* __restrict__ bp,
                                                  const __hip_bfloat16* __restrict__ XA16,
                                                  const float* __restrict__ XBp,
                                                  float* __restrict__ out_pos,
                                                  float* __restrict__ out_struct) {
    const int n = blockIdx.x;
    const int t = threadIdx.x;   // 0..127
    __shared__ float pos_lds[KNN][129];   // 16.5 KB, (k+j)%32 banks -> 2-way max
    __shared__ float d_lds[KNN];
    __shared__ int   idx_lds[KNN];
    __shared__ float red0[KNN], red1[KNN];

    // distance MLP: d(n,k) = sum_o relu(s*w1d[o]+b1d[o])*w2d[o] + b2d ; 4 lanes/k
    {
        int k = t >> 2, sub = t & 3;
        float s = dists[(size_t)n * KNN + k];
        float a = 0.f;
        int ob = sub * 32;
        #pragma unroll
        for (int o4 = 0; o4 < 8; ++o4) {
            float4 w1 = ((const float4*)(w1d + ob))[o4];
            float4 b1 = ((const float4*)(b1d + ob))[o4];
            float4 w2 = ((const float4*)(w2d + ob))[o4];
            a += fmaxf(fmaf(s, w1.x, b1.x), 0.f) * w2.x;
            a += fmaxf(fmaf(s, w1.y, b1.y), 0.f) * w2.y;
            a += fmaxf(fmaf(s, w1.z, b1.z), 0.f) * w2.z;
            a += fmaxf(fmaf(s, w1.w, b1.w), 0.f) * w2.w;
        }
        a += __shfl_xor(a, 1);
        a += __shfl_xor(a, 2);
        if (sub == 0) d_lds[k] = a + b2d[0];
        if (t < KNN) idx_lds[t] = argm[(size_t)n * KNN + t];
    }

    float base = XBp[(size_t)n * DOUT + t];   // XB + bh, per-channel
    float wpv  = wp[t];
    __syncthreads();

    float sacc = 0.f;
    #pragma unroll 8
    for (int kk = 0; kk < KNN; ++kk) {
        float dk = d_lds[kk];                         // broadcast read
        int   m  = idx_lds[kk];                       // broadcast read
        float xa = __bfloat162float(XA16[(size_t)m * DOUT + t]);  // coalesced gather
        float h  = fmaxf(fmaf(dk, xa, base), 0.f);
        sacc += h;
        pos_lds[kk][t] = h * wpv;                     // 1 ds_write, no chain
    }
    out_struct[(size_t)n * DOUT + t] = sacc * (1.f / KNN);
    __syncthreads();

    // position reduce: k2 = t&31, sub2 = t>>5 covers channel quarter sub2*32..+31
    {
        int k2 = t & 31, sub2 = t >> 5;
        const float* row = pos_lds[k2];
        float p = 0.f;
        #pragma unroll
        for (int j = 0; j < 32; ++j) p += row[sub2 * 32 + j];   // (k2+j)%32: conflict-free
        p += __shfl_xor(p, 32);   // wave0: quarters 0+1 ; wave1: quarters 2+3
        if (t < 32)                 red0[t] = p;
        else if (t >= 64 && t < 96) red1[t - 64] = p;
    }
    __syncthreads();
    if (t < KNN)
        out_pos[(size_t)n * KNN + t] = red0[t] + red1[t] + bp[0];
}

extern "C" void kernel_launch(void* const* d_in, const int* in_sizes, int n_in,
                              void* d_out, int out_size, void* d_ws, size_t ws_size,
                              hipStream_t stream) {
    const float* data_x = (const float*)d_in[0];
    const float* dists  = (const float*)d_in[1];
    const int*   argm   = (const int*)d_in[2];
    const float* w1d    = (const float*)d_in[3];
    const float* b1d    = (const float*)d_in[4];
    const float* w2d    = (const float*)d_in[5];
    const float* b2d    = (const float*)d_in[6];
    const float* wh     = (const float*)d_in[7];
    const float* bh     = (const float*)d_in[8];
    const float* wp     = (const float*)d_in[9];
    const float* bp     = (const float*)d_in[10];

    float* out_pos    = (float*)d_out;                       // [N,K]
    float* out_struct = out_pos + (size_t)N_ROWS * KNN;      // [N,DOUT]

    float*          XBp  = (float*)d_ws;                                  // [N,128] f32
    __hip_bfloat16* XA16 = (__hip_bfloat16*)(XBp + (size_t)N_ROWS * DOUT);// [N,128] bf16
    float*          WTp  = (float*)((char*)XA16 + (size_t)N_ROWS * DOUT * 2); // 32768 f32

    pack_wt<<<128, 256, 0, stream>>>(wh, WTp);
    gemm_xaxb<<<N_ROWS / 32, 256, 0, stream>>>(data_x, WTp, bh, XA16, XBp);
    fused_main<<<N_ROWS, 128, 0, stream>>>(dists, argm, w1d, b1d, w2d, b2d,
                                           wp, bp, XA16, XBp, out_pos, out_struct);
}

// Round 8
// 170.504 us; speedup vs baseline: 1.8117x; 1.3537x over previous
//
#include <hip/hip_runtime.h>
#include <hip/hip_bf16.h>

#define N_ROWS 20000
#define KNN 32
#define DIN 128
#define DOUT 128

// ---- kernel 0: pack transposed/fused weight layout ----
// WTp float layout: [d4][j][i] where d = d4*4+i, j in [0,256)
//   j <  128 : channel j of XA (wh[j][d]) ; j >= 128 : channel j-128 of XB (wh[j-128][128+d])
__global__ __launch_bounds__(256) void pack_wt(const float* __restrict__ wh,
                                               float* __restrict__ WTp) {
    int tid = blockIdx.x * 256 + threadIdx.x;  // 0..32767
    int i  = tid & 3;
    int j  = (tid >> 2) & 255;
    int d4 = tid >> 10;
    int d  = d4 * 4 + i;
    float v = (j < 128) ? wh[j * 256 + d] : wh[(j - 128) * 256 + 128 + d];
    WTp[tid] = v;
}

// ---- kernel 1: XA16[n][o] = bf16(x[n]·wh[o,:128]) ; XBp[n][o] = x[n]·wh[o,128:] + bh[o]
// 32-row tiles (625 blocks), 256 threads: tx = t&63 (channel), ty = t>>6, 8 rows/thread
__global__ __launch_bounds__(256) void gemm_xaxb(const float* __restrict__ x,
                                                 const float* __restrict__ WTp,
                                                 const float* __restrict__ bh,
                                                 __hip_bfloat16* __restrict__ XA16,
                                                 float* __restrict__ XBp) {
    __shared__ float xs[32][128];   // 16 KB
    const int t = threadIdx.x;
    const int row0 = blockIdx.x * 32;   // 625*32 == 20000 exactly, no bounds needed

    #pragma unroll
    for (int i = 0; i < 4; ++i) {
        int idx = t + i * 256;          // float4 slot in [0,1024)
        int r = idx >> 5, c4 = idx & 31;
        ((float4*)xs[r])[c4] = ((const float4*)(x + (size_t)(row0 + r) * DIN))[c4];
    }
    __syncthreads();

    const int tx = t & 63;
    const int ty = t >> 6;
    const int r0 = ty * 8;
    float acc[8][4];
    #pragma unroll
    for (int r = 0; r < 8; ++r)
        #pragma unroll
        for (int c = 0; c < 4; ++c) acc[r][c] = 0.f;

    const float4* W4 = (const float4*)WTp;
    for (int d4 = 0; d4 < 32; ++d4) {
        float4 w0 = W4[d4 * 256 + tx];         // XA, channel tx
        float4 w1 = W4[d4 * 256 + 64 + tx];    // XA, channel tx+64
        float4 w2 = W4[d4 * 256 + 128 + tx];   // XB, channel tx
        float4 w3 = W4[d4 * 256 + 192 + tx];   // XB, channel tx+64
        #pragma unroll
        for (int r = 0; r < 8; ++r) {
            float4 xv = ((const float4*)xs[r0 + r])[d4];  // wave-uniform broadcast
            acc[r][0] += xv.x * w0.x + xv.y * w0.y + xv.z * w0.z + xv.w * w0.w;
            acc[r][1] += xv.x * w1.x + xv.y * w1.y + xv.z * w1.z + xv.w * w1.w;
            acc[r][2] += xv.x * w2.x + xv.y * w2.y + xv.z * w2.z + xv.w * w2.w;
            acc[r][3] += xv.x * w3.x + xv.y * w3.y + xv.z * w3.z + xv.w * w3.w;
        }
    }

    float bh0 = bh[tx], bh1 = bh[64 + tx];
    #pragma unroll
    for (int r = 0; r < 8; ++r) {
        size_t gr = row0 + r0 + r;
        XA16[gr * DOUT + tx]       = __float2bfloat16(acc[r][0]);
        XA16[gr * DOUT + 64 + tx]  = __float2bfloat16(acc[r][1]);
        XBp [gr * DOUT + tx]       = acc[r][2] + bh0;
        XBp [gr * DOUT + 64 + tx]  = acc[r][3] + bh1;
    }
}

// ---- kernel 2: fused distance-MLP + bf16 gather + relu + pos/structure reductions
// 128 threads = 2 independent waves, wave w handles n = blockIdx*2 + w.
// Lane owns 2 channels (uint = 2 bf16): one gather row = ONE 256B wave load.
// Full unroll -> up to 32 gathers in flight. Structure acc is wave-local.
__global__ __launch_bounds__(128) void fused_main(const float* __restrict__ dists,
                                                  const int*  __restrict__ argm,
                                                  const float* __restrict__ w1d,
                                                  const float* __restrict__ b1d,
                                                  const float* __restrict__ w2d,
                                                  const float* __restrict__ b2d,
                                                  const float* __restrict__ wp,
                                                  const float* __restrict__ bp,
                                                  const __hip_bfloat16* __restrict__ XA16,
                                                  const float* __restrict__ XBp,
                                                  float* __restrict__ out_pos,
                                                  float* __restrict__ out_struct) {
    const int w    = threadIdx.x >> 6;           // wave id: which n of the pair
    const int lane = threadIdx.x & 63;
    const int n    = blockIdx.x * 2 + w;

    __shared__ float pos_lds[2][KNN][65];        // stride 65: (k+j)%32 conflict-free
    __shared__ float d_lds[2][KNN];
    __shared__ int   idx_lds[2][KNN];

    // distance MLP: d(n,k) = sum_o relu(s*w1d[o]+b1d[o])*w2d[o] + b2d
    // 2 lanes per k (sub = lane&1 handles 64 channels), 1 shfl to combine
    {
        int k = lane >> 1, sub = lane & 1;
        float s = dists[(size_t)n * KNN + k];
        float a = 0.f;
        int ob = sub * 64;
        #pragma unroll
        for (int o4 = 0; o4 < 16; ++o4) {
            float4 w1 = ((const float4*)(w1d + ob))[o4];
            float4 b1 = ((const float4*)(b1d + ob))[o4];
            float4 w2 = ((const float4*)(w2d + ob))[o4];
            a += fmaxf(fmaf(s, w1.x, b1.x), 0.f) * w2.x;
            a += fmaxf(fmaf(s, w1.y, b1.y), 0.f) * w2.y;
            a += fmaxf(fmaf(s, w1.z, b1.z), 0.f) * w2.z;
            a += fmaxf(fmaf(s, w1.w, b1.w), 0.f) * w2.w;
        }
        a += __shfl_xor(a, 1);
        if (sub == 0) d_lds[w][k] = a + b2d[0];
        if (lane < KNN) idx_lds[w][lane] = argm[(size_t)n * KNN + lane];
    }

    // per-lane channel pair c = {2*lane, 2*lane+1}
    float2 base = *(const float2*)(XBp + (size_t)n * DOUT + lane * 2);
    float2 wpv  = *(const float2*)(wp + lane * 2);
    __syncthreads();

    const unsigned short* xa_base = (const unsigned short*)XA16;
    float s0 = 0.f, s1 = 0.f;
    #pragma unroll
    for (int kk = 0; kk < KNN; ++kk) {
        float dk = d_lds[w][kk];                  // LDS broadcast
        int   m  = idx_lds[w][kk];                // LDS broadcast (wave-uniform)
        unsigned u = *(const unsigned*)(xa_base + (size_t)m * DOUT + lane * 2);
        float xa0 = __uint_as_float(u << 16);            // low bf16
        float xa1 = __uint_as_float(u & 0xFFFF0000u);    // high bf16
        float h0 = fmaxf(fmaf(dk, xa0, base.x), 0.f);
        float h1 = fmaxf(fmaf(dk, xa1, base.y), 0.f);
        s0 += h0; s1 += h1;
        pos_lds[w][kk][lane] = fmaf(h1, wpv.y, h0 * wpv.x);
    }
    *(float2*)(out_struct + (size_t)n * DOUT + lane * 2) =
        make_float2(s0 * (1.f / KNN), s1 * (1.f / KNN));
    __syncthreads();

    // position reduce: lane -> (k2 = lane&31, half = lane>>5); 32 scalar LDS reads
    // bank = (k2 + j) % 32 within each half -> conflict-free (halves 2-way = free)
    {
        int k2 = lane & 31, half = lane >> 5;
        const float* row = &pos_lds[w][k2][half * 32];
        float p = 0.f;
        #pragma unroll
        for (int j = 0; j < 32; ++j) p += row[j];
        p += __shfl_xor(p, 32);
        if (lane < KNN)
            out_pos[(size_t)n * KNN + lane] = p + bp[0];
    }
}

extern "C" void kernel_launch(void* const* d_in, const int* in_sizes, int n_in,
                              void* d_out, int out_size, void* d_ws, size_t ws_size,
                              hipStream_t stream) {
    const float* data_x = (const float*)d_in[0];
    const float* dists  = (const float*)d_in[1];
    const int*   argm   = (const int*)d_in[2];
    const float* w1d    = (const float*)d_in[3];
    const float* b1d    = (const float*)d_in[4];
    const float* w2d    = (const float*)d_in[5];
    const float* b2d    = (const float*)d_in[6];
    const float* wh     = (const float*)d_in[7];
    const float* bh     = (const float*)d_in[8];
    const float* wp     = (const float*)d_in[9];
    const float* bp     = (const float*)d_in[10];

    float* out_pos    = (float*)d_out;                       // [N,K]
    float* out_struct = out_pos + (size_t)N_ROWS * KNN;      // [N,DOUT]

    float*          XBp  = (float*)d_ws;                                  // [N,128] f32
    __hip_bfloat16* XA16 = (__hip_bfloat16*)(XBp + (size_t)N_ROWS * DOUT);// [N,128] bf16
    float*          WTp  = (float*)((char*)XA16 + (size_t)N_ROWS * DOUT * 2); // 32768 f32

    pack_wt<<<128, 256, 0, stream>>>(wh, WTp);
    gemm_xaxb<<<N_ROWS / 32, 256, 0, stream>>>(data_x, WTp, bh, XA16, XBp);
    fused_main<<<N_ROWS / 2, 128, 0, stream>>>(dists, argm, w1d, b1d, w2d, b2d,
                                               wp, bp, XA16, XBp, out_pos, out_struct);
}